// Round 17
// baseline (116.132 us; speedup 1.0000x reference)
//
#include <hip/hip_runtime.h>
#include <hip/hip_bf16.h>
#include <stdint.h>

// Problem constants
#define L_TOT 2304   // 48*48
#define D_IN  64
#define NF    32     // features per head
#define NH    8      // heads
#define NB    2      // batch
#define MW    256    // MLP width = NH*NF
#define CHS   8      // l-chunks for stats pass
#define NSTRIP (L_TOT/32)   // 72 m-strips

constexpr float EPSV  = 1e-5f;
// Q pre-scale: log2(e)/sqrt(32). Scores in log2 domain; s in [0, ~8.2],
// 2^s <= ~290, Z <= 7e5 -> no max-shift needed (Q,K >= 0 after ReLU).
constexpr float SCALE2 = 0.2550351f;

#if __has_builtin(__builtin_amdgcn_exp2f)
#define EXP2(x) __builtin_amdgcn_exp2f(x)   // single v_exp_f32 (domain safe: s>=0)
#else
#define EXP2(x) exp2f(x)
#endif

typedef __bf16  bf16x8  __attribute__((ext_vector_type(8)));
typedef float   f32x16  __attribute__((ext_vector_type(16)));
typedef float   f32x4   __attribute__((ext_vector_type(4)));

union U32x4BF { uint32_t u[4]; bf16x8 v; };

// Pack two f32 -> one u32 of two bf16 (element 0 = low halfword = a).
static __device__ __forceinline__ uint32_t pack_bf16(float a, float b) {
    union { __bf16 h[2]; uint32_t u; } r;
    r.h[0] = (__bf16)a;
    r.h[1] = (__bf16)b;
    return r.u;
}

// ---------------------------------------------------------------------------
// Kernel 0 (merged prep): job-indexed transposes to bf16.
//   jobs 0..127  : W1/W2 32x32 transpose tiles -> W1t/W2t [out][in]
//   jobs 128..151: Wqkv[mtx][h][d][f] -> Wt[(mtx*8+h)][f][d]
//   jobs 152..295: x[n][d][l-tile] -> xb[n][l][d]
// block = 256, grid = 296
// ---------------------------------------------------------------------------
__global__ __launch_bounds__(256) void k_prep(
    const float* __restrict__ x,
    const float* __restrict__ Wq, const float* __restrict__ Wk, const float* __restrict__ Wv,
    const float* __restrict__ W1, const float* __restrict__ W2,
    __hip_bfloat16* __restrict__ xb, __hip_bfloat16* __restrict__ Wqkvt,
    __hip_bfloat16* __restrict__ W1t, __hip_bfloat16* __restrict__ W2t)
{
    const int job = blockIdx.x;
    const int tx = threadIdx.x & 31, ty = threadIdx.x >> 5;
    __shared__ float t[64][33];

    if (job < 128) {
        const int z = job >> 6;            // 0: W1, 1: W2
        const int tt = job & 63;
        const int bi = (tt >> 3) * 32, bj = (tt & 7) * 32;
        const float* src = z ? W2 : W1;
        __hip_bfloat16* dst = z ? W2t : W1t;
        #pragma unroll
        for (int k = 0; k < 4; ++k)
            t[ty + 8 * k][tx] = src[(size_t)(bi + ty + 8 * k) * MW + bj + tx];
        __syncthreads();
        #pragma unroll
        for (int k = 0; k < 4; ++k)
            dst[(size_t)(bj + ty + 8 * k) * MW + bi + tx] =
                __float2bfloat16(t[tx][ty + 8 * k]);
        return;
    }

    const float* src;
    size_t sstride;
    __hip_bfloat16* dst;
    if (job < 152) {
        int j = job - 128;                 // mtx*8 + h
        int mtx = j >> 3, h = j & 7;
        const float* Wm = mtx == 0 ? Wq : (mtx == 1 ? Wk : Wv);
        src = Wm + (size_t)h * D_IN * NF;
        sstride = NF;
        dst = Wqkvt + (size_t)j * NF * D_IN;
    } else {
        int i = job - 152;
        int n = i / NSTRIP, lt = i % NSTRIP;
        src = x + (size_t)n * D_IN * L_TOT + lt * 32;
        sstride = L_TOT;
        dst = xb + ((size_t)n * L_TOT + lt * 32) * D_IN;
    }
    #pragma unroll
    for (int k = 0; k < 8; ++k)
        t[ty + 8 * k][tx] = src[(size_t)(ty + 8 * k) * sstride + tx];
    __syncthreads();
    #pragma unroll
    for (int k = 0; k < 4; ++k) {
        int col = ty + 8 * k;
        #pragma unroll
        for (int j = 0; j < 2; ++j)
            dst[(size_t)col * D_IN + tx + 32 * j] = __float2bfloat16(t[tx + 32 * j][col]);
    }
}

// ---------------------------------------------------------------------------
// Kernel 1 (MFMA proj, mtx-split): one matrix per block. 8 waves = 8 heads.
// block = 512, grid = (72 ltiles, 2 n, 3 mtx)
// ---------------------------------------------------------------------------
__global__ __launch_bounds__(512) void k_proj(
    const __hip_bfloat16* __restrict__ xb, const __hip_bfloat16* __restrict__ Wqkvt,
    const float* __restrict__ bq, const float* __restrict__ bk, const float* __restrict__ bv,
    __hip_bfloat16* __restrict__ Qo, __hip_bfloat16* __restrict__ Ko,
    __hip_bfloat16* __restrict__ Vt)
{
    const int ltile = blockIdx.x;
    const int n = blockIdx.y;
    const int mtx = blockIdx.z;
    const int h = threadIdx.x >> 6;       // wave = head
    const int l0 = ltile * 32;
    const int lane = threadIdx.x & 63;
    const int c = lane & 31, hi = lane >> 5;
    const int hn = h * NB + n;

    const bf16x8* xp = reinterpret_cast<const bf16x8*>(
        xb + ((size_t)n * L_TOT + l0 + c) * D_IN);
    bf16x8 xf[4];
    #pragma unroll
    for (int t = 0; t < 4; ++t) xf[t] = xp[2 * t + hi];

    const float* bsp = mtx == 0 ? bq : (mtx == 1 ? bk : bv);

    const bf16x8* wp = reinterpret_cast<const bf16x8*>(
        Wqkvt + ((size_t)(mtx * NH + h) * NF + c) * D_IN);
    f32x16 acc = {};
    #pragma unroll
    for (int t = 0; t < 4; ++t)
        acc = __builtin_amdgcn_mfma_f32_32x32x16_bf16(wp[2 * t + hi], xf[t], acc, 0, 0, 0);

    float bb[16];
    #pragma unroll
    for (int g = 0; g < 4; ++g) {
        float4 t4 = *reinterpret_cast<const float4*>(&bsp[h * NF + 8 * g + 4 * hi]);
        bb[4 * g + 0] = t4.x; bb[4 * g + 1] = t4.y;
        bb[4 * g + 2] = t4.z; bb[4 * g + 3] = t4.w;
    }

    float v[16], s = 0.f, s2 = 0.f;
    #pragma unroll
    for (int r = 0; r < 16; ++r) {
        v[r] = acc[r] + bb[r];
        s += v[r]; s2 += v[r] * v[r];
    }
    s  += __shfl_xor(s, 32, 64);
    s2 += __shfl_xor(s2, 32, 64);
    float mu = s * (1.f / 32);
    float rstd = rsqrtf(s2 * (1.f / 32) - mu * mu + EPSV);
    float y[16];
    #pragma unroll
    for (int r = 0; r < 16; ++r) y[r] = fmaxf((v[r] - mu) * rstd, 0.f);

    if (mtx == 2) {
        #pragma unroll
        for (int r = 0; r < 16; ++r) {
            int f = (r & 3) + 8 * (r >> 2) + 4 * hi;
            Vt[((size_t)(hn * NSTRIP + ltile) * NF + f) * 32 + c] = __float2bfloat16(y[r]);
        }
    } else {
        if (mtx == 0) {
            #pragma unroll
            for (int r = 0; r < 16; ++r) y[r] *= SCALE2;
        }
        uint32_t pk[8];
        #pragma unroll
        for (int q = 0; q < 8; ++q) pk[q] = pack_bf16(y[2 * q], y[2 * q + 1]);
        uint32_t rr[4];
        #pragma unroll
        for (int j = 0; j < 4; ++j)
            rr[j] = (uint32_t)__shfl_xor((int)(hi ? pk[j] : pk[4 + j]), 32, 64);
        uint32_t row[8];
        if (hi == 0) {
            row[0] = pk[0]; row[1] = pk[1]; row[2] = rr[0]; row[3] = rr[1];
            row[4] = pk[2]; row[5] = pk[3]; row[6] = rr[2]; row[7] = rr[3];
        } else {
            row[0] = rr[0]; row[1] = rr[1]; row[2] = pk[4]; row[3] = pk[5];
            row[4] = rr[2]; row[5] = rr[3]; row[6] = pk[6]; row[7] = pk[7];
        }
        __hip_bfloat16* dst = (mtx == 0 ? Qo : Ko)
            + ((size_t)hn * L_TOT + l0 + c) * NF + hi * 16;
        reinterpret_cast<uint4*>(dst)[0] = make_uint4(row[0], row[1], row[2], row[3]);
        reinterpret_cast<uint4*>(dst)[1] = make_uint4(row[4], row[5], row[6], row[7]);
    }
}

// ---------------------------------------------------------------------------
// Kernel 2: column softmax stats, S-orientation: S = Q @ K^T (A = Q rows l,
// B = K cols m). Lane c owns column m = strip*32+c; Z[m] = in-register sum
// over 16 C-regs (row perm irrelevant for a full-column sum) + 1 shfl.
// Output zpart in NATURAL m order. block = 256, grid = (18, 16 hn, CHS=8)
// ---------------------------------------------------------------------------
__global__ __launch_bounds__(256) void k_stats(
    const __hip_bfloat16* __restrict__ Qb, const __hip_bfloat16* __restrict__ Kb,
    float* __restrict__ zpart)
{
    const int w = threadIdx.x >> 6;
    const int strip = blockIdx.x * 4 + w;
    const int hn = blockIdx.y;
    const int chunk = blockIdx.z;
    const int lane = threadIdx.x & 63;
    const int c = lane & 31, hi = lane >> 5;

    // K B-fragments (held): lane c = col m = strip*32+c
    const bf16x8* kp = reinterpret_cast<const bf16x8*>(
        Kb + ((size_t)hn * L_TOT + strip * 32 + c) * NF);
    const bf16x8 kb0 = kp[hi];
    const bf16x8 kb1 = kp[2 + hi];

    float z0 = 0.f, z1 = 0.f, z2 = 0.f, z3 = 0.f;

    for (int it = 0; it < (L_TOT / 32) / CHS; ++it) {
        const int l0 = (chunk * ((L_TOT / 32) / CHS) + it) * 32;
        const bf16x8* qp = reinterpret_cast<const bf16x8*>(
            Qb + ((size_t)hn * L_TOT + l0 + c) * NF);
        f32x16 s16 = {};
        s16 = __builtin_amdgcn_mfma_f32_32x32x16_bf16(qp[hi], kb0, s16, 0, 0, 0);
        s16 = __builtin_amdgcn_mfma_f32_32x32x16_bf16(qp[2 + hi], kb1, s16, 0, 0, 0);
        #pragma unroll
        for (int r = 0; r < 4; ++r) z0 += EXP2(s16[r]);
        #pragma unroll
        for (int r = 4; r < 8; ++r) z1 += EXP2(s16[r]);
        #pragma unroll
        for (int r = 8; r < 12; ++r) z2 += EXP2(s16[r]);
        #pragma unroll
        for (int r = 12; r < 16; ++r) z3 += EXP2(s16[r]);
    }
    float Z = (z0 + z1) + (z2 + z3);
    Z += __shfl_xor(Z, 32, 64);
    if (hi == 0)
        zpart[((size_t)chunk * 16 + hn) * L_TOT + strip * 32 + c] = Z;
}

// ---------------------------------------------------------------------------
// Kernel 2b (micro): zinv[hn][m] = 1 / sum_k zpart[k][hn][m]
// block = 256, grid = (16 hn, 9)
// ---------------------------------------------------------------------------
__global__ __launch_bounds__(256) void k_zinv(
    const float* __restrict__ zpart, float* __restrict__ zinv)
{
    const int hn = blockIdx.x;
    const int m = blockIdx.y * 256 + threadIdx.x;
    float Z = 0.f;
    #pragma unroll
    for (int k = 0; k < CHS; ++k)
        Z += zpart[((size_t)k * 16 + hn) * L_TOT + m];
    zinv[(size_t)hn * L_TOT + m] = 1.f / Z;
}

// ---------------------------------------------------------------------------
// Kernel 3: apply, QBLK=64, global zinv (no LDS prologue; 32 KB LDS total).
// 8 waves split the m-loop (9 strips each); K/V fragments loaded once per
// strip feed BOTH l-tiles. p = 2^s16 * zinv[m] (zi loaded per strip from L2).
// block = 512, grid = (36, 16)
// ---------------------------------------------------------------------------
static __device__ __forceinline__ void make_pfrags(
    const f32x16& s16, const float* __restrict__ zi, int hi,
    U32x4BF& fragP0, U32x4BF& fragP1)
{
    float p[16];
    #pragma unroll
    for (int r = 0; r < 16; ++r) p[r] = EXP2(s16[r]) * zi[r];

    uint32_t wp[8];
    #pragma unroll
    for (int q = 0; q < 8; ++q) wp[q] = pack_bf16(p[2 * q], p[2 * q + 1]);

    uint32_t sendA = hi ? wp[0] : wp[2];
    uint32_t sendB = hi ? wp[1] : wp[3];
    uint32_t rA = (uint32_t)__shfl_xor((int)sendA, 32, 64);
    uint32_t rB = (uint32_t)__shfl_xor((int)sendB, 32, 64);
    fragP0.u[0] = hi ? rA    : wp[0];
    fragP0.u[1] = hi ? rB    : wp[1];
    fragP0.u[2] = hi ? wp[2] : rA;
    fragP0.u[3] = hi ? wp[3] : rB;
    uint32_t sendC = hi ? wp[4] : wp[6];
    uint32_t sendD = hi ? wp[5] : wp[7];
    uint32_t rC = (uint32_t)__shfl_xor((int)sendC, 32, 64);
    uint32_t rD = (uint32_t)__shfl_xor((int)sendD, 32, 64);
    fragP1.u[0] = hi ? rC    : wp[4];
    fragP1.u[1] = hi ? rD    : wp[5];
    fragP1.u[2] = hi ? wp[6] : rC;
    fragP1.u[3] = hi ? wp[7] : rD;
}

__global__ __launch_bounds__(512) void k_apply(
    const __hip_bfloat16* __restrict__ Qb, const __hip_bfloat16* __restrict__ Kb,
    const __hip_bfloat16* __restrict__ Vt, const float* __restrict__ zinv,
    float* __restrict__ partA)
{
    const int w = threadIdx.x >> 6;          // m-range index 0..7
    const int l0 = blockIdx.x * 64;
    const int hn = blockIdx.y;
    const int lane = threadIdx.x & 63;
    const int c = lane & 31, hi = lane >> 5;

    const bf16x8* qp0 = reinterpret_cast<const bf16x8*>(
        Qb + ((size_t)hn * L_TOT + l0 + c) * NF);
    const bf16x8* qp1 = reinterpret_cast<const bf16x8*>(
        Qb + ((size_t)hn * L_TOT + l0 + 32 + c) * NF);
    const bf16x8 qa0 = qp0[hi], qa1 = qp0[2 + hi];
    const bf16x8 qc0 = qp1[hi], qc1 = qp1[2 + hi];

    f32x16 acc0 = {}, acc1 = {};

    #pragma unroll 3
    for (int it = 0; it < NSTRIP / 8; ++it) {
        const int st = w * (NSTRIP / 8) + it;
        const bf16x8* kp = reinterpret_cast<const bf16x8*>(
            Kb + ((size_t)hn * L_TOT + st * 32 + c) * NF);
        const bf16x8 kf0 = kp[hi], kf1 = kp[2 + hi];
        const bf16x8* vp = reinterpret_cast<const bf16x8*>(
            Vt + ((size_t)(hn * NSTRIP + st) * NF + c) * 32);
        const bf16x8 vf0 = vp[hi], vf1 = vp[2 + hi];

        // zinv for this strip's 16 C-rows: row(r,hi) = (r&3)+8*(r>>2)+4*hi
        // -> 4 contiguous float4 at offsets 4*hi + {0,8,16,24}
        const float* zb = zinv + (size_t)hn * L_TOT + st * 32 + 4 * hi;
        const float4 z0 = *reinterpret_cast<const float4*>(zb + 0);
        const float4 z1 = *reinterpret_cast<const float4*>(zb + 8);
        const float4 z2 = *reinterpret_cast<const float4*>(zb + 16);
        const float4 z3 = *reinterpret_cast<const float4*>(zb + 24);
        float zi[16];
        zi[0] = z0.x;  zi[1] = z0.y;  zi[2] = z0.z;  zi[3] = z0.w;
        zi[4] = z1.x;  zi[5] = z1.y;  zi[6] = z1.z;  zi[7] = z1.w;
        zi[8] = z2.x;  zi[9] = z2.y;  zi[10] = z2.z; zi[11] = z2.w;
        zi[12] = z3.x; zi[13] = z3.y; zi[14] = z3.z; zi[15] = z3.w;

        // tile 0
        {
            f32x16 s16 = {};
            s16 = __builtin_amdgcn_mfma_f32_32x32x16_bf16(kf0, qa0, s16, 0, 0, 0);
            s16 = __builtin_amdgcn_mfma_f32_32x32x16_bf16(kf1, qa1, s16, 0, 0, 0);
            U32x4BF fragP0, fragP1;
            make_pfrags(s16, zi, hi, fragP0, fragP1);
            acc0 = __builtin_amdgcn_mfma_f32_32x32x16_bf16(fragP0.v, vf0, acc0, 0, 0, 0);
            acc0 = __builtin_amdgcn_mfma_f32_32x32x16_bf16(fragP1.v, vf1, acc0, 0, 0, 0);
        }
        // tile 1
        {
            f32x16 s16 = {};
            s16 = __builtin_amdgcn_mfma_f32_32x32x16_bf16(kf0, qc0, s16, 0, 0, 0);
            s16 = __builtin_amdgcn_mfma_f32_32x32x16_bf16(kf1, qc1, s16, 0, 0, 0);
            U32x4BF fragP0, fragP1;
            make_pfrags(s16, zi, hi, fragP0, fragP1);
            acc1 = __builtin_amdgcn_mfma_f32_32x32x16_bf16(fragP0.v, vf0, acc1, 0, 0, 0);
            acc1 = __builtin_amdgcn_mfma_f32_32x32x16_bf16(fragP1.v, vf1, acc1, 0, 0, 0);
        }
    }

    // LDS reduction of 8 per-wave partials, one tile at a time (32 KB buffer)
    __shared__ float red[8][16][64];
    const int n = hn & 1, h = hn >> 1;

    #pragma unroll
    for (int r = 0; r < 16; ++r) red[w][r][lane] = acc0[r];
    __syncthreads();
    {
        float* outp = partA + ((size_t)(n * L_TOT + l0)) * MW + h * NF + c;
        #pragma unroll
        for (int j = 0; j < 2; ++j) {
            const int r = 2 * w + j;
            float sv = 0.f;
            #pragma unroll
            for (int k = 0; k < 8; ++k) sv += red[k][r][lane];
            const int row = (r & 3) + 8 * (r >> 2) + 4 * hi;
            outp[(size_t)row * MW] = sv;
        }
    }
    __syncthreads();
    #pragma unroll
    for (int r = 0; r < 16; ++r) red[w][r][lane] = acc1[r];
    __syncthreads();
    {
        float* outp = partA + ((size_t)(n * L_TOT + l0 + 32)) * MW + h * NF + c;
        #pragma unroll
        for (int j = 0; j < 2; ++j) {
            const int r = 2 * w + j;
            float sv = 0.f;
            #pragma unroll
            for (int k = 0; k < 8; ++k) sv += red[k][r][lane];
            const int row = (r & 3) + 8 * (r >> 2) + 4 * hi;
            outp[(size_t)row * MW] = sv;
        }
    }
}

// ---------------------------------------------------------------------------
// Kernel 4 (MFMA MLP, 16x16x32): m=relu(relu(h@W1+b1)@W2+b2);
//   o = gamma*inorm(m+h)+beta; out[n,c,l].
// 16 rows/block, 512 thr (8 waves x 32 cols), grid = 288 (full GPU).
// ---------------------------------------------------------------------------
__global__ __launch_bounds__(512) void k_mlp(
    const float* __restrict__ partA,
    const __hip_bfloat16* __restrict__ W1t, const float* __restrict__ b1,
    const __hip_bfloat16* __restrict__ W2t, const float* __restrict__ b2,
    const float* __restrict__ gamma, const float* __restrict__ beta,
    float* __restrict__ out)
{
    const int blk = blockIdx.x;
    const int n  = blk / (L_TOT / 16);
    const int l0 = (blk % (L_TOT / 16)) * 16;
    const int tid = threadIdx.x;
    const int w = tid >> 6, lane = tid & 63;
    const int ar = lane & 15;      // A-row / B-col within 16
    const int kg = lane >> 4;      // k-group 0..3
    const int n0 = w * 32;

    __shared__ __align__(16) char smem[50176];
    float (*hsf)[MW] = reinterpret_cast<float (*)[MW]>(smem);
    __hip_bfloat16 (*hA)[264]  = reinterpret_cast<__hip_bfloat16 (*)[264]>(smem + 16384);
    __hip_bfloat16 (*msb)[264] = reinterpret_cast<__hip_bfloat16 (*)[264]>(smem + 24832);
    float (*ys)[MW] = reinterpret_cast<float (*)[MW]>(smem + 33280);
    float (*rs)[4]  = reinterpret_cast<float (*)[4]>(smem + 49664);
    float (*rs2)[4] = reinterpret_cast<float (*)[4]>(smem + 49920);

    for (int idx = tid; idx < 16 * MW; idx += 512) {
        int r = idx >> 8, i = idx & 255;
        float v = partA[((size_t)n * L_TOT + l0 + r) * MW + i];
        hsf[r][i] = v;
        hA[r][i] = __float2bfloat16(v);
    }
    __syncthreads();

    // ---- layer 1: wave covers cols [n0, n0+32) as two 16-col subtiles ----
    f32x4 acc0 = {}, acc1 = {};
    {
        const __hip_bfloat16* B0p = W1t + (size_t)(n0 + ar) * MW + kg * 8;
        const __hip_bfloat16* B1p = W1t + (size_t)(n0 + 16 + ar) * MW + kg * 8;
        #pragma unroll
        for (int ks = 0; ks < 8; ++ks) {
            bf16x8 a  = *reinterpret_cast<const bf16x8*>(&hA[ar][ks * 32 + kg * 8]);
            bf16x8 b0 = *reinterpret_cast<const bf16x8*>(B0p + ks * 32);
            bf16x8 b1v = *reinterpret_cast<const bf16x8*>(B1p + ks * 32);
            acc0 = __builtin_amdgcn_mfma_f32_16x16x32_bf16(a, b0, acc0, 0, 0, 0);
            acc1 = __builtin_amdgcn_mfma_f32_16x16x32_bf16(a, b1v, acc1, 0, 0, 0);
        }
    }
    {
        const float bb0 = b1[n0 + ar], bb1 = b1[n0 + 16 + ar];
        #pragma unroll
        for (int r = 0; r < 4; ++r) {
            int row = kg * 4 + r;
            msb[row][n0 + ar]      = __float2bfloat16(fmaxf(acc0[r] + bb0, 0.f));
            msb[row][n0 + 16 + ar] = __float2bfloat16(fmaxf(acc1[r] + bb1, 0.f));
        }
    }
    __syncthreads();

    // ---- layer 2 + residual ----
    f32x4 a20 = {}, a21 = {};
    {
        const __hip_bfloat16* B0p = W2t + (size_t)(n0 + ar) * MW + kg * 8;
        const __hip_bfloat16* B1p = W2t + (size_t)(n0 + 16 + ar) * MW + kg * 8;
        #pragma unroll
        for (int ks = 0; ks < 8; ++ks) {
            bf16x8 a  = *reinterpret_cast<const bf16x8*>(&msb[ar][ks * 32 + kg * 8]);
            bf16x8 b0 = *reinterpret_cast<const bf16x8*>(B0p + ks * 32);
            bf16x8 b1v = *reinterpret_cast<const bf16x8*>(B1p + ks * 32);
            a20 = __builtin_amdgcn_mfma_f32_16x16x32_bf16(a, b0, a20, 0, 0, 0);
            a21 = __builtin_amdgcn_mfma_f32_16x16x32_bf16(a, b1v, a21, 0, 0, 0);
        }
    }
    {
        const float bb0 = b2[n0 + ar], bb1 = b2[n0 + 16 + ar];
        #pragma unroll
        for (int r = 0; r < 4; ++r) {
            int row = kg * 4 + r;
            ys[row][n0 + ar]      = fmaxf(a20[r] + bb0, 0.f) + hsf[row][n0 + ar];
            ys[row][n0 + 16 + ar] = fmaxf(a21[r] + bb1, 0.f) + hsf[row][n0 + 16 + ar];
        }
    }
    __syncthreads();

    // ---- instance norm over 256 channels per row + transposed store ----
    const int col = tid & 255;
    const int half = tid >> 8;          // 2 halves x 8 rows
    const int wid = (tid >> 6) & 3;
    float vv[8];
    #pragma unroll
    for (int r = 0; r < 8; ++r) {
        float v = ys[half * 8 + r][col];
        vv[r] = v;
        float s = v, s2 = v * v;
        #pragma unroll
        for (int o = 32; o >= 1; o >>= 1) { s += __shfl_xor(s, o, 64); s2 += __shfl_xor(s2, o, 64); }
        if (lane == 0) { rs[half * 8 + r][wid] = s; rs2[half * 8 + r][wid] = s2; }
    }
    __syncthreads();
    const float g = gamma[col], be = beta[col];
    float ov[8];
    #pragma unroll
    for (int r = 0; r < 8; ++r) {
        int row = half * 8 + r;
        float s  = rs[row][0]  + rs[row][1]  + rs[row][2]  + rs[row][3];
        float s2 = rs2[row][0] + rs2[row][1] + rs2[row][2] + rs2[row][3];
        float mu  = s  * (1.f / MW);
        float var = s2 * (1.f / MW) - mu * mu;
        ov[r] = g * ((vv[r] - mu) * rsqrtf(var + EPSV)) + be;
    }
    float* ob = out + ((size_t)n * MW + col) * L_TOT + l0 + half * 8;
    reinterpret_cast<float4*>(ob)[0] = make_float4(ov[0], ov[1], ov[2], ov[3]);
    reinterpret_cast<float4*>(ob)[1] = make_float4(ov[4], ov[5], ov[6], ov[7]);
}

// ---------------------------------------------------------------------------
extern "C" void kernel_launch(void* const* d_in, const int* in_sizes, int n_in,
                              void* d_out, int out_size, void* d_ws, size_t ws_size,
                              hipStream_t stream) {
    const float* x  = (const float*)d_in[0];
    const float* Wq = (const float*)d_in[1];
    const float* bq = (const float*)d_in[2];
    const float* Wk = (const float*)d_in[3];
    const float* bk = (const float*)d_in[4];
    const float* Wv = (const float*)d_in[5];
    const float* bv = (const float*)d_in[6];
    const float* W1 = (const float*)d_in[7];
    const float* b1 = (const float*)d_in[8];
    const float* W2 = (const float*)d_in[9];
    const float* b2 = (const float*)d_in[10];
    const float* gm = (const float*)d_in[11];
    const float* bt = (const float*)d_in[12];
    float* out = (float*)d_out;

    const size_t QKVE = (size_t)16 * L_TOT * NF;   // 1,179,648 bf16 elems each
    const size_t XBE  = (size_t)NB * L_TOT * D_IN; // 294,912
    const size_t WQE  = (size_t)3 * NH * NF * D_IN;// 49,152
    const size_t WTE  = (size_t)MW * MW;           // 65,536 per matrix
    const size_t ZN = (size_t)CHS * 16 * L_TOT;
    const size_t LN = (size_t)16 * L_TOT;

    __hip_bfloat16* Qb = (__hip_bfloat16*)d_ws;
    __hip_bfloat16* Kb = Qb + QKVE;
    __hip_bfloat16* Vt = Kb + QKVE;
    __hip_bfloat16* xb = Vt + QKVE;
    __hip_bfloat16* Wqkvt = xb + XBE;
    __hip_bfloat16* W1t = Wqkvt + WQE;
    __hip_bfloat16* W2t = W1t + WTE;
    float* zpart = (float*)(W2t + WTE);
    float* zinv  = zpart + ZN;
    float* partA = zinv + LN;

    k_prep<<<dim3(296), dim3(256), 0, stream>>>(
        x, Wq, Wk, Wv, W1, W2, xb, Wqkvt, W1t, W2t);
    k_proj<<<dim3(NSTRIP, NB, 3), dim3(512), 0, stream>>>(
        xb, Wqkvt, bq, bk, bv, Qb, Kb, Vt);
    k_stats<<<dim3(NSTRIP / 4, 16, CHS), dim3(256), 0, stream>>>(Qb, Kb, zpart);
    k_zinv<<<dim3(16, L_TOT / 256), dim3(256), 0, stream>>>(zpart, zinv);
    k_apply<<<dim3(NSTRIP / 2, 16), dim3(512), 0, stream>>>(
        Qb, Kb, Vt, zinv, partA);
    k_mlp<<<dim3(NB * (L_TOT / 16)), dim3(512), 0, stream>>>(
        partA, W1t, b1, W2t, b2, gm, bt, out);
}

// Round 18
// 109.447 us; speedup vs baseline: 1.0611x; 1.0611x over previous
//
#include <hip/hip_runtime.h>
#include <hip/hip_bf16.h>
#include <stdint.h>

// Problem constants
#define L_TOT 2304   // 48*48
#define D_IN  64
#define NF    32     // features per head
#define NH    8      // heads
#define NB    2      // batch
#define MW    256    // MLP width = NH*NF
#define CHS   8      // l-chunks for stats pass
#define NSTRIP (L_TOT/32)   // 72 m-strips

constexpr float EPSV  = 1e-5f;
// Q pre-scale: log2(e)/sqrt(32). Scores in log2 domain; s in [0, ~8.2],
// 2^s <= ~290, Z <= 7e5 -> no max-shift needed (Q,K >= 0 after ReLU).
constexpr float SCALE2 = 0.2550351f;

#if __has_builtin(__builtin_amdgcn_exp2f)
#define EXP2(x) __builtin_amdgcn_exp2f(x)   // single v_exp_f32 (domain safe: s>=0)
#else
#define EXP2(x) exp2f(x)
#endif

typedef __bf16  bf16x8  __attribute__((ext_vector_type(8)));
typedef float   f32x16  __attribute__((ext_vector_type(16)));
typedef float   f32x4   __attribute__((ext_vector_type(4)));

union U32x4BF { uint32_t u[4]; bf16x8 v; };

// Pack two f32 -> one u32 of two bf16 (element 0 = low halfword = a).
static __device__ __forceinline__ uint32_t pack_bf16(float a, float b) {
    union { __bf16 h[2]; uint32_t u; } r;
    r.h[0] = (__bf16)a;
    r.h[1] = (__bf16)b;
    return r.u;
}

// ---------------------------------------------------------------------------
// Kernel 0 (merged prep): job-indexed transposes to bf16.
//   jobs 0..127  : W1/W2 32x32 transpose tiles -> W1t/W2t [out][in]
//   jobs 128..151: Wqkv[mtx][h][d][f] -> Wt[(mtx*8+h)][f][d]
//   jobs 152..295: x[n][d][l-tile] -> xb[n][l][d]
// block = 256, grid = 296
// ---------------------------------------------------------------------------
__global__ __launch_bounds__(256) void k_prep(
    const float* __restrict__ x,
    const float* __restrict__ Wq, const float* __restrict__ Wk, const float* __restrict__ Wv,
    const float* __restrict__ W1, const float* __restrict__ W2,
    __hip_bfloat16* __restrict__ xb, __hip_bfloat16* __restrict__ Wqkvt,
    __hip_bfloat16* __restrict__ W1t, __hip_bfloat16* __restrict__ W2t)
{
    const int job = blockIdx.x;
    const int tx = threadIdx.x & 31, ty = threadIdx.x >> 5;
    __shared__ float t[64][33];

    if (job < 128) {
        const int z = job >> 6;            // 0: W1, 1: W2
        const int tt = job & 63;
        const int bi = (tt >> 3) * 32, bj = (tt & 7) * 32;
        const float* src = z ? W2 : W1;
        __hip_bfloat16* dst = z ? W2t : W1t;
        #pragma unroll
        for (int k = 0; k < 4; ++k)
            t[ty + 8 * k][tx] = src[(size_t)(bi + ty + 8 * k) * MW + bj + tx];
        __syncthreads();
        #pragma unroll
        for (int k = 0; k < 4; ++k)
            dst[(size_t)(bj + ty + 8 * k) * MW + bi + tx] =
                __float2bfloat16(t[tx][ty + 8 * k]);
        return;
    }

    const float* src;
    size_t sstride;
    __hip_bfloat16* dst;
    if (job < 152) {
        int j = job - 128;                 // mtx*8 + h
        int mtx = j >> 3, h = j & 7;
        const float* Wm = mtx == 0 ? Wq : (mtx == 1 ? Wk : Wv);
        src = Wm + (size_t)h * D_IN * NF;
        sstride = NF;
        dst = Wqkvt + (size_t)j * NF * D_IN;
    } else {
        int i = job - 152;
        int n = i / NSTRIP, lt = i % NSTRIP;
        src = x + (size_t)n * D_IN * L_TOT + lt * 32;
        sstride = L_TOT;
        dst = xb + ((size_t)n * L_TOT + lt * 32) * D_IN;
    }
    #pragma unroll
    for (int k = 0; k < 8; ++k)
        t[ty + 8 * k][tx] = src[(size_t)(ty + 8 * k) * sstride + tx];
    __syncthreads();
    #pragma unroll
    for (int k = 0; k < 4; ++k) {
        int col = ty + 8 * k;
        #pragma unroll
        for (int j = 0; j < 2; ++j)
            dst[(size_t)col * D_IN + tx + 32 * j] = __float2bfloat16(t[tx + 32 * j][col]);
    }
}

// ---------------------------------------------------------------------------
// Kernel 1 (MFMA proj, mtx-split): one matrix per block. 8 waves = 8 heads.
// block = 512, grid = (72 ltiles, 2 n, 3 mtx)
// ---------------------------------------------------------------------------
__global__ __launch_bounds__(512) void k_proj(
    const __hip_bfloat16* __restrict__ xb, const __hip_bfloat16* __restrict__ Wqkvt,
    const float* __restrict__ bq, const float* __restrict__ bk, const float* __restrict__ bv,
    __hip_bfloat16* __restrict__ Qo, __hip_bfloat16* __restrict__ Ko,
    __hip_bfloat16* __restrict__ Vt)
{
    const int ltile = blockIdx.x;
    const int n = blockIdx.y;
    const int mtx = blockIdx.z;
    const int h = threadIdx.x >> 6;       // wave = head
    const int l0 = ltile * 32;
    const int lane = threadIdx.x & 63;
    const int c = lane & 31, hi = lane >> 5;
    const int hn = h * NB + n;

    const bf16x8* xp = reinterpret_cast<const bf16x8*>(
        xb + ((size_t)n * L_TOT + l0 + c) * D_IN);
    bf16x8 xf[4];
    #pragma unroll
    for (int t = 0; t < 4; ++t) xf[t] = xp[2 * t + hi];

    const float* bsp = mtx == 0 ? bq : (mtx == 1 ? bk : bv);

    const bf16x8* wp = reinterpret_cast<const bf16x8*>(
        Wqkvt + ((size_t)(mtx * NH + h) * NF + c) * D_IN);
    f32x16 acc = {};
    #pragma unroll
    for (int t = 0; t < 4; ++t)
        acc = __builtin_amdgcn_mfma_f32_32x32x16_bf16(wp[2 * t + hi], xf[t], acc, 0, 0, 0);

    float bb[16];
    #pragma unroll
    for (int g = 0; g < 4; ++g) {
        float4 t4 = *reinterpret_cast<const float4*>(&bsp[h * NF + 8 * g + 4 * hi]);
        bb[4 * g + 0] = t4.x; bb[4 * g + 1] = t4.y;
        bb[4 * g + 2] = t4.z; bb[4 * g + 3] = t4.w;
    }

    float v[16], s = 0.f, s2 = 0.f;
    #pragma unroll
    for (int r = 0; r < 16; ++r) {
        v[r] = acc[r] + bb[r];
        s += v[r]; s2 += v[r] * v[r];
    }
    s  += __shfl_xor(s, 32, 64);
    s2 += __shfl_xor(s2, 32, 64);
    float mu = s * (1.f / 32);
    float rstd = rsqrtf(s2 * (1.f / 32) - mu * mu + EPSV);
    float y[16];
    #pragma unroll
    for (int r = 0; r < 16; ++r) y[r] = fmaxf((v[r] - mu) * rstd, 0.f);

    if (mtx == 2) {
        #pragma unroll
        for (int r = 0; r < 16; ++r) {
            int f = (r & 3) + 8 * (r >> 2) + 4 * hi;
            Vt[((size_t)(hn * NSTRIP + ltile) * NF + f) * 32 + c] = __float2bfloat16(y[r]);
        }
    } else {
        if (mtx == 0) {
            #pragma unroll
            for (int r = 0; r < 16; ++r) y[r] *= SCALE2;
        }
        uint32_t pk[8];
        #pragma unroll
        for (int q = 0; q < 8; ++q) pk[q] = pack_bf16(y[2 * q], y[2 * q + 1]);
        uint32_t rr[4];
        #pragma unroll
        for (int j = 0; j < 4; ++j)
            rr[j] = (uint32_t)__shfl_xor((int)(hi ? pk[j] : pk[4 + j]), 32, 64);
        uint32_t row[8];
        if (hi == 0) {
            row[0] = pk[0]; row[1] = pk[1]; row[2] = rr[0]; row[3] = rr[1];
            row[4] = pk[2]; row[5] = pk[3]; row[6] = rr[2]; row[7] = rr[3];
        } else {
            row[0] = rr[0]; row[1] = rr[1]; row[2] = pk[4]; row[3] = pk[5];
            row[4] = rr[2]; row[5] = rr[3]; row[6] = pk[6]; row[7] = pk[7];
        }
        __hip_bfloat16* dst = (mtx == 0 ? Qo : Ko)
            + ((size_t)hn * L_TOT + l0 + c) * NF + hi * 16;
        reinterpret_cast<uint4*>(dst)[0] = make_uint4(row[0], row[1], row[2], row[3]);
        reinterpret_cast<uint4*>(dst)[1] = make_uint4(row[4], row[5], row[6], row[7]);
    }
}

// ---------------------------------------------------------------------------
// Kernel 2: column softmax stats, S-orientation: S = Q @ K^T (A = Q rows l,
// B = K cols m). Lane c owns column m = strip*32+c; Z[m] = in-register sum
// over 16 C-regs (row perm irrelevant for a full-column sum) + 1 shfl.
// Output zpart in NATURAL m order. block = 256, grid = (18, 16 hn, CHS=8)
// ---------------------------------------------------------------------------
__global__ __launch_bounds__(256) void k_stats(
    const __hip_bfloat16* __restrict__ Qb, const __hip_bfloat16* __restrict__ Kb,
    float* __restrict__ zpart)
{
    const int w = threadIdx.x >> 6;
    const int strip = blockIdx.x * 4 + w;
    const int hn = blockIdx.y;
    const int chunk = blockIdx.z;
    const int lane = threadIdx.x & 63;
    const int c = lane & 31, hi = lane >> 5;

    // K B-fragments (held): lane c = col m = strip*32+c
    const bf16x8* kp = reinterpret_cast<const bf16x8*>(
        Kb + ((size_t)hn * L_TOT + strip * 32 + c) * NF);
    const bf16x8 kb0 = kp[hi];
    const bf16x8 kb1 = kp[2 + hi];

    float z0 = 0.f, z1 = 0.f, z2 = 0.f, z3 = 0.f;

    for (int it = 0; it < (L_TOT / 32) / CHS; ++it) {
        const int l0 = (chunk * ((L_TOT / 32) / CHS) + it) * 32;
        const bf16x8* qp = reinterpret_cast<const bf16x8*>(
            Qb + ((size_t)hn * L_TOT + l0 + c) * NF);
        f32x16 s16 = {};
        s16 = __builtin_amdgcn_mfma_f32_32x32x16_bf16(qp[hi], kb0, s16, 0, 0, 0);
        s16 = __builtin_amdgcn_mfma_f32_32x32x16_bf16(qp[2 + hi], kb1, s16, 0, 0, 0);
        #pragma unroll
        for (int r = 0; r < 4; ++r) z0 += EXP2(s16[r]);
        #pragma unroll
        for (int r = 4; r < 8; ++r) z1 += EXP2(s16[r]);
        #pragma unroll
        for (int r = 8; r < 12; ++r) z2 += EXP2(s16[r]);
        #pragma unroll
        for (int r = 12; r < 16; ++r) z3 += EXP2(s16[r]);
    }
    float Z = (z0 + z1) + (z2 + z3);
    Z += __shfl_xor(Z, 32, 64);
    if (hi == 0)
        zpart[((size_t)chunk * 16 + hn) * L_TOT + strip * 32 + c] = Z;
}

// ---------------------------------------------------------------------------
// Kernel 3: apply, QBLK=64, fused zinv. Per block: LDS-reduce zpart for this
// hn -> zinv_s[2304]; 8 waves split the m-loop (9 strips each); K/V fragments
// loaded once per strip feed BOTH l-tiles. p = 2^s16 * zinv[m].
// block = 512, grid = (36, 16)
// ---------------------------------------------------------------------------
static __device__ __forceinline__ void make_pfrags(
    const f32x16& s16, const float* __restrict__ zi, int hi,
    U32x4BF& fragP0, U32x4BF& fragP1)
{
    float p[16];
    #pragma unroll
    for (int r = 0; r < 16; ++r) p[r] = EXP2(s16[r]) * zi[r];

    uint32_t wp[8];
    #pragma unroll
    for (int q = 0; q < 8; ++q) wp[q] = pack_bf16(p[2 * q], p[2 * q + 1]);

    uint32_t sendA = hi ? wp[0] : wp[2];
    uint32_t sendB = hi ? wp[1] : wp[3];
    uint32_t rA = (uint32_t)__shfl_xor((int)sendA, 32, 64);
    uint32_t rB = (uint32_t)__shfl_xor((int)sendB, 32, 64);
    fragP0.u[0] = hi ? rA    : wp[0];
    fragP0.u[1] = hi ? rB    : wp[1];
    fragP0.u[2] = hi ? wp[2] : rA;
    fragP0.u[3] = hi ? wp[3] : rB;
    uint32_t sendC = hi ? wp[4] : wp[6];
    uint32_t sendD = hi ? wp[5] : wp[7];
    uint32_t rC = (uint32_t)__shfl_xor((int)sendC, 32, 64);
    uint32_t rD = (uint32_t)__shfl_xor((int)sendD, 32, 64);
    fragP1.u[0] = hi ? rC    : wp[4];
    fragP1.u[1] = hi ? rD    : wp[5];
    fragP1.u[2] = hi ? wp[6] : rC;
    fragP1.u[3] = hi ? wp[7] : rD;
}

__global__ __launch_bounds__(512) void k_apply(
    const __hip_bfloat16* __restrict__ Qb, const __hip_bfloat16* __restrict__ Kb,
    const __hip_bfloat16* __restrict__ Vt, const float* __restrict__ zpart,
    float* __restrict__ partA)
{
    const int w = threadIdx.x >> 6;          // m-range index 0..7
    const int l0 = blockIdx.x * 64;
    const int hn = blockIdx.y;
    const int lane = threadIdx.x & 63;
    const int c = lane & 31, hi = lane >> 5;

    // zinv for the whole hn row (natural m order)
    __shared__ float zinv_s[L_TOT];
    for (int m = threadIdx.x; m < L_TOT; m += 512) {
        float Z = 0.f;
        #pragma unroll
        for (int k = 0; k < CHS; ++k)
            Z += zpart[((size_t)k * 16 + hn) * L_TOT + m];
        zinv_s[m] = 1.f / Z;
    }
    __syncthreads();

    const bf16x8* qp0 = reinterpret_cast<const bf16x8*>(
        Qb + ((size_t)hn * L_TOT + l0 + c) * NF);
    const bf16x8* qp1 = reinterpret_cast<const bf16x8*>(
        Qb + ((size_t)hn * L_TOT + l0 + 32 + c) * NF);
    const bf16x8 qa0 = qp0[hi], qa1 = qp0[2 + hi];
    const bf16x8 qc0 = qp1[hi], qc1 = qp1[2 + hi];

    f32x16 acc0 = {}, acc1 = {};

    #pragma unroll 3
    for (int it = 0; it < NSTRIP / 8; ++it) {
        const int st = w * (NSTRIP / 8) + it;
        const bf16x8* kp = reinterpret_cast<const bf16x8*>(
            Kb + ((size_t)hn * L_TOT + st * 32 + c) * NF);
        const bf16x8 kf0 = kp[hi], kf1 = kp[2 + hi];
        const bf16x8* vp = reinterpret_cast<const bf16x8*>(
            Vt + ((size_t)(hn * NSTRIP + st) * NF + c) * 32);
        const bf16x8 vf0 = vp[hi], vf1 = vp[2 + hi];

        // zinv for this strip's 16 C-rows (m = st*32 + rowperm(r,hi))
        float zi[16];
        #pragma unroll
        for (int r = 0; r < 16; ++r)
            zi[r] = zinv_s[st * 32 + (r & 3) + 8 * (r >> 2) + 4 * hi];

        // tile 0
        {
            f32x16 s16 = {};
            s16 = __builtin_amdgcn_mfma_f32_32x32x16_bf16(kf0, qa0, s16, 0, 0, 0);
            s16 = __builtin_amdgcn_mfma_f32_32x32x16_bf16(kf1, qa1, s16, 0, 0, 0);
            U32x4BF fragP0, fragP1;
            make_pfrags(s16, zi, hi, fragP0, fragP1);
            acc0 = __builtin_amdgcn_mfma_f32_32x32x16_bf16(fragP0.v, vf0, acc0, 0, 0, 0);
            acc0 = __builtin_amdgcn_mfma_f32_32x32x16_bf16(fragP1.v, vf1, acc0, 0, 0, 0);
        }
        // tile 1
        {
            f32x16 s16 = {};
            s16 = __builtin_amdgcn_mfma_f32_32x32x16_bf16(kf0, qc0, s16, 0, 0, 0);
            s16 = __builtin_amdgcn_mfma_f32_32x32x16_bf16(kf1, qc1, s16, 0, 0, 0);
            U32x4BF fragP0, fragP1;
            make_pfrags(s16, zi, hi, fragP0, fragP1);
            acc1 = __builtin_amdgcn_mfma_f32_32x32x16_bf16(fragP0.v, vf0, acc1, 0, 0, 0);
            acc1 = __builtin_amdgcn_mfma_f32_32x32x16_bf16(fragP1.v, vf1, acc1, 0, 0, 0);
        }
    }

    // LDS reduction of 8 per-wave partials, one tile at a time (32 KB buffer)
    __shared__ float red[8][16][64];
    const int n = hn & 1, h = hn >> 1;

    #pragma unroll
    for (int r = 0; r < 16; ++r) red[w][r][lane] = acc0[r];
    __syncthreads();
    {
        float* outp = partA + ((size_t)(n * L_TOT + l0)) * MW + h * NF + c;
        #pragma unroll
        for (int j = 0; j < 2; ++j) {
            const int r = 2 * w + j;
            float sv = 0.f;
            #pragma unroll
            for (int k = 0; k < 8; ++k) sv += red[k][r][lane];
            const int row = (r & 3) + 8 * (r >> 2) + 4 * hi;
            outp[(size_t)row * MW] = sv;
        }
    }
    __syncthreads();
    #pragma unroll
    for (int r = 0; r < 16; ++r) red[w][r][lane] = acc1[r];
    __syncthreads();
    {
        float* outp = partA + ((size_t)(n * L_TOT + l0 + 32)) * MW + h * NF + c;
        #pragma unroll
        for (int j = 0; j < 2; ++j) {
            const int r = 2 * w + j;
            float sv = 0.f;
            #pragma unroll
            for (int k = 0; k < 8; ++k) sv += red[k][r][lane];
            const int row = (r & 3) + 8 * (r >> 2) + 4 * hi;
            outp[(size_t)row * MW] = sv;
        }
    }
}

// ---------------------------------------------------------------------------
// Kernel 4 (MFMA MLP, 16x16x32): m=relu(relu(h@W1+b1)@W2+b2);
//   o = gamma*inorm(m+h)+beta; out[n,c,l].
// 16 rows/block, 512 thr (8 waves x 32 cols), grid = 288 (full GPU).
// ---------------------------------------------------------------------------
__global__ __launch_bounds__(512) void k_mlp(
    const float* __restrict__ partA,
    const __hip_bfloat16* __restrict__ W1t, const float* __restrict__ b1,
    const __hip_bfloat16* __restrict__ W2t, const float* __restrict__ b2,
    const float* __restrict__ gamma, const float* __restrict__ beta,
    float* __restrict__ out)
{
    const int blk = blockIdx.x;
    const int n  = blk / (L_TOT / 16);
    const int l0 = (blk % (L_TOT / 16)) * 16;
    const int tid = threadIdx.x;
    const int w = tid >> 6, lane = tid & 63;
    const int ar = lane & 15;      // A-row / B-col within 16
    const int kg = lane >> 4;      // k-group 0..3
    const int n0 = w * 32;

    __shared__ __align__(16) char smem[50176];
    float (*hsf)[MW] = reinterpret_cast<float (*)[MW]>(smem);
    __hip_bfloat16 (*hA)[264]  = reinterpret_cast<__hip_bfloat16 (*)[264]>(smem + 16384);
    __hip_bfloat16 (*msb)[264] = reinterpret_cast<__hip_bfloat16 (*)[264]>(smem + 24832);
    float (*ys)[MW] = reinterpret_cast<float (*)[MW]>(smem + 33280);
    float (*rs)[4]  = reinterpret_cast<float (*)[4]>(smem + 49664);
    float (*rs2)[4] = reinterpret_cast<float (*)[4]>(smem + 49920);

    for (int idx = tid; idx < 16 * MW; idx += 512) {
        int r = idx >> 8, i = idx & 255;
        float v = partA[((size_t)n * L_TOT + l0 + r) * MW + i];
        hsf[r][i] = v;
        hA[r][i] = __float2bfloat16(v);
    }
    __syncthreads();

    // ---- layer 1: wave covers cols [n0, n0+32) as two 16-col subtiles ----
    f32x4 acc0 = {}, acc1 = {};
    {
        const __hip_bfloat16* B0p = W1t + (size_t)(n0 + ar) * MW + kg * 8;
        const __hip_bfloat16* B1p = W1t + (size_t)(n0 + 16 + ar) * MW + kg * 8;
        #pragma unroll
        for (int ks = 0; ks < 8; ++ks) {
            bf16x8 a  = *reinterpret_cast<const bf16x8*>(&hA[ar][ks * 32 + kg * 8]);
            bf16x8 b0 = *reinterpret_cast<const bf16x8*>(B0p + ks * 32);
            bf16x8 b1v = *reinterpret_cast<const bf16x8*>(B1p + ks * 32);
            acc0 = __builtin_amdgcn_mfma_f32_16x16x32_bf16(a, b0, acc0, 0, 0, 0);
            acc1 = __builtin_amdgcn_mfma_f32_16x16x32_bf16(a, b1v, acc1, 0, 0, 0);
        }
    }
    {
        const float bb0 = b1[n0 + ar], bb1 = b1[n0 + 16 + ar];
        #pragma unroll
        for (int r = 0; r < 4; ++r) {
            int row = kg * 4 + r;
            msb[row][n0 + ar]      = __float2bfloat16(fmaxf(acc0[r] + bb0, 0.f));
            msb[row][n0 + 16 + ar] = __float2bfloat16(fmaxf(acc1[r] + bb1, 0.f));
        }
    }
    __syncthreads();

    // ---- layer 2 + residual ----
    f32x4 a20 = {}, a21 = {};
    {
        const __hip_bfloat16* B0p = W2t + (size_t)(n0 + ar) * MW + kg * 8;
        const __hip_bfloat16* B1p = W2t + (size_t)(n0 + 16 + ar) * MW + kg * 8;
        #pragma unroll
        for (int ks = 0; ks < 8; ++ks) {
            bf16x8 a  = *reinterpret_cast<const bf16x8*>(&msb[ar][ks * 32 + kg * 8]);
            bf16x8 b0 = *reinterpret_cast<const bf16x8*>(B0p + ks * 32);
            bf16x8 b1v = *reinterpret_cast<const bf16x8*>(B1p + ks * 32);
            a20 = __builtin_amdgcn_mfma_f32_16x16x32_bf16(a, b0, a20, 0, 0, 0);
            a21 = __builtin_amdgcn_mfma_f32_16x16x32_bf16(a, b1v, a21, 0, 0, 0);
        }
    }
    {
        const float bb0 = b2[n0 + ar], bb1 = b2[n0 + 16 + ar];
        #pragma unroll
        for (int r = 0; r < 4; ++r) {
            int row = kg * 4 + r;
            ys[row][n0 + ar]      = fmaxf(a20[r] + bb0, 0.f) + hsf[row][n0 + ar];
            ys[row][n0 + 16 + ar] = fmaxf(a21[r] + bb1, 0.f) + hsf[row][n0 + 16 + ar];
        }
    }
    __syncthreads();

    // ---- instance norm over 256 channels per row + transposed store ----
    const int col = tid & 255;
    const int half = tid >> 8;          // 2 halves x 8 rows
    const int wid = (tid >> 6) & 3;
    float vv[8];
    #pragma unroll
    for (int r = 0; r < 8; ++r) {
        float v = ys[half * 8 + r][col];
        vv[r] = v;
        float s = v, s2 = v * v;
        #pragma unroll
        for (int o = 32; o >= 1; o >>= 1) { s += __shfl_xor(s, o, 64); s2 += __shfl_xor(s2, o, 64); }
        if (lane == 0) { rs[half * 8 + r][wid] = s; rs2[half * 8 + r][wid] = s2; }
    }
    __syncthreads();
    const float g = gamma[col], be = beta[col];
    float ov[8];
    #pragma unroll
    for (int r = 0; r < 8; ++r) {
        int row = half * 8 + r;
        float s  = rs[row][0]  + rs[row][1]  + rs[row][2]  + rs[row][3];
        float s2 = rs2[row][0] + rs2[row][1] + rs2[row][2] + rs2[row][3];
        float mu  = s  * (1.f / MW);
        float var = s2 * (1.f / MW) - mu * mu;
        ov[r] = g * ((vv[r] - mu) * rsqrtf(var + EPSV)) + be;
    }
    float* ob = out + ((size_t)n * MW + col) * L_TOT + l0 + half * 8;
    reinterpret_cast<float4*>(ob)[0] = make_float4(ov[0], ov[1], ov[2], ov[3]);
    reinterpret_cast<float4*>(ob)[1] = make_float4(ov[4], ov[5], ov[6], ov[7]);
}

// ---------------------------------------------------------------------------
extern "C" void kernel_launch(void* const* d_in, const int* in_sizes, int n_in,
                              void* d_out, int out_size, void* d_ws, size_t ws_size,
                              hipStream_t stream) {
    const float* x  = (const float*)d_in[0];
    const float* Wq = (const float*)d_in[1];
    const float* bq = (const float*)d_in[2];
    const float* Wk = (const float*)d_in[3];
    const float* bk = (const float*)d_in[4];
    const float* Wv = (const float*)d_in[5];
    const float* bv = (const float*)d_in[6];
    const float* W1 = (const float*)d_in[7];
    const float* b1 = (const float*)d_in[8];
    const float* W2 = (const float*)d_in[9];
    const float* b2 = (const float*)d_in[10];
    const float* gm = (const float*)d_in[11];
    const float* bt = (const float*)d_in[12];
    float* out = (float*)d_out;

    const size_t QKVE = (size_t)16 * L_TOT * NF;   // 1,179,648 bf16 elems each
    const size_t XBE  = (size_t)NB * L_TOT * D_IN; // 294,912
    const size_t WQE  = (size_t)3 * NH * NF * D_IN;// 49,152
    const size_t WTE  = (size_t)MW * MW;           // 65,536 per matrix
    const size_t ZN = (size_t)CHS * 16 * L_TOT;

    __hip_bfloat16* Qb = (__hip_bfloat16*)d_ws;
    __hip_bfloat16* Kb = Qb + QKVE;
    __hip_bfloat16* Vt = Kb + QKVE;
    __hip_bfloat16* xb = Vt + QKVE;
    __hip_bfloat16* Wqkvt = xb + XBE;
    __hip_bfloat16* W1t = Wqkvt + WQE;
    __hip_bfloat16* W2t = W1t + WTE;
    float* zpart = (float*)(W2t + WTE);
    float* partA = zpart + ZN;

    k_prep<<<dim3(296), dim3(256), 0, stream>>>(
        x, Wq, Wk, Wv, W1, W2, xb, Wqkvt, W1t, W2t);
    k_proj<<<dim3(NSTRIP, NB, 3), dim3(512), 0, stream>>>(
        xb, Wqkvt, bq, bk, bv, Qb, Kb, Vt);
    k_stats<<<dim3(NSTRIP / 4, 16, CHS), dim3(256), 0, stream>>>(Qb, Kb, zpart);
    k_apply<<<dim3(NSTRIP / 2, 16), dim3(512), 0, stream>>>(
        Qb, Kb, Vt, zpart, partA);
    k_mlp<<<dim3(NB * (L_TOT / 16)), dim3(512), 0, stream>>>(
        partA, W1t, b1, W2t, b2, gm, bt, out);
}